// Round 8
// baseline (78.148 us; speedup 1.0000x reference)
//
#include <hip/hip_runtime.h>
#include <hip/hip_bf16.h>
#include <math.h>

#define BB 8
#define TT 2048
#define DD 512
#define NT2 8   // 256-col tiles per batch row

typedef __attribute__((ext_vector_type(8))) short bf16x8;
typedef __attribute__((ext_vector_type(4))) float f32x4;

__device__ inline float softplus_f(float v) { return log1pf(expf(v)); }

// fast tanh: 1 - 2/(exp2(2*log2e*y)+1); v_exp_f32 + v_rcp_f32, ~1e-6 rel err
__device__ inline float tanh_fast(float y) {
    float e = __builtin_amdgcn_exp2f(y * 2.8853900817779268f);
    return 1.0f - 2.0f * __builtin_amdgcn_rcpf(e + 1.0f);
}
__device__ inline float exp_fast(float y) {
    return __builtin_amdgcn_exp2f(y * 1.4426950408889634f);
}

// fp32 -> bf16 round-nearest-even on bit pattern
__device__ inline unsigned short f2bf(float f) {
    unsigned int u = __float_as_uint(f);
    unsigned int r = (u + 0x7fffu + ((u >> 16) & 1u)) >> 16;
    return (unsigned short)r;
}
__device__ inline float bf2f(unsigned short h) {
    unsigned int u = ((unsigned int)h) << 16;
    return __uint_as_float(u);
}

__device__ inline void load_lds16(const void* g, void* l) {
    __builtin_amdgcn_global_load_lds(
        (const __attribute__((address_space(1))) unsigned int*)g,
        (__attribute__((address_space(3))) unsigned int*)l, 16, 0, 0);
}

// ---------------- K1: fused prep + per-row elementwise + reductions ----------------
// 256 threads = 4 waves; one wave per row of D=512; 8 elems/thread.
// Writes XN (normalized x, bf16) and PO (gelu*gate_hist*gate_cos, bf16).
__global__ __launch_bounds__(256) void k1_elem(
    const float* __restrict__ x, const float* __restrict__ ema_mean,
    const float* __restrict__ ema_sq, const float* __restrict__ ema_out,
    const float* __restrict__ p_log_tau, const float* __restrict__ p_lbu,
    const float* __restrict__ p_lbd, const float* __restrict__ p_lg,
    unsigned short* __restrict__ xn, unsigned short* __restrict__ po) {
    const int row = blockIdx.x * 4 + (threadIdx.x >> 6);
    const int lane = threadIdx.x & 63;
    const size_t base = (size_t)row * DD;

    const float tau = expf(p_log_tau[0]);
    const float beta_up = softplus_f(p_lbu[0]);
    const float beta_dn = softplus_f(p_lbd[0]);
    const float gamma = softplus_f(p_lg[0]);

    float xv[8], pg[8];
    float sx2 = 0.f, so2 = 0.f, sod = 0.f, se2 = 0.f;
#pragma unroll
    for (int c = 0; c < 2; ++c) {
        const int j0 = c * 256 + lane * 4;
        float4 xx = *reinterpret_cast<const float4*>(x + base + j0);
        float4 mm = *reinterpret_cast<const float4*>(ema_mean + j0);
        float4 qq = *reinterpret_cast<const float4*>(ema_sq + j0);
        float4 eo = *reinterpret_cast<const float4*>(ema_out + j0);
        float vv[4] = {xx.x, xx.y, xx.z, xx.w};
        float vm[4] = {mm.x, mm.y, mm.z, mm.w};
        float vq[4] = {qq.x, qq.y, qq.z, qq.w};
        float ve[4] = {eo.x, eo.y, eo.z, eo.w};
#pragma unroll
        for (int q = 0; q < 4; ++q) {
            const int e = c * 4 + q;
            float xf = vv[q];
            xv[e] = xf;
            // gelu (tanh approx)
            float x3 = xf * xf * xf;
            float gl = 0.5f * xf * (1.0f + tanh_fast(0.7978845608028654f * (xf + 0.044715f * x3)));
            // z-gate (inv_std inline)
            float var = fmaxf(vq[q] - vm[q] * vm[q], 1e-4f);
            float istd = __builtin_amdgcn_rcpf(sqrtf(var) + 1e-5f);
            float z = (xf - vm[q]) * istd;
            float th = tanh_fast(gamma * z);
            float up = beta_up * fmaxf(th, 0.0f);
            float dn = beta_dn * fmaxf(-th, 0.0f);
            float gh = fminf(fmaxf(1.0f + up - dn, 0.05f), 8.0f);
            pg[e] = gl * gh;
            sx2 += xf * xf;
            so2 += gl * gl;
            sod += gl * ve[q];
            se2 += ve[q] * ve[q];
        }
    }
#pragma unroll
    for (int off = 32; off; off >>= 1) {
        sx2 += __shfl_xor(sx2, off);
        so2 += __shfl_xor(so2, off);
        sod += __shfl_xor(sod, off);
        se2 += __shfl_xor(se2, off);
    }
    const float inv_xnorm = __builtin_amdgcn_rcpf(fmaxf(sqrtf(sx2), 1e-12f));
    const float inv_en = __builtin_amdgcn_rcpf(fmaxf(sqrtf(se2), 1e-12f));
    float cosv = sod * inv_en * __builtin_amdgcn_rcpf(fmaxf(sqrtf(so2), 1e-12f));
    cosv = fminf(fmaxf(cosv, -1.0f), 1.0f);
    const float gcos = exp_fast(-tau * cosv);

#pragma unroll
    for (int c = 0; c < 2; ++c) {
        const int j0 = c * 256 + lane * 4;
        ushort4 pb;
        pb.x = f2bf(pg[c * 4 + 0] * gcos);
        pb.y = f2bf(pg[c * 4 + 1] * gcos);
        pb.z = f2bf(pg[c * 4 + 2] * gcos);
        pb.w = f2bf(pg[c * 4 + 3] * gcos);
        *reinterpret_cast<ushort4*>(po + base + j0) = pb;
        ushort4 xb;
        xb.x = f2bf(xv[c * 4 + 0] * inv_xnorm);
        xb.y = f2bf(xv[c * 4 + 1] * inv_xnorm);
        xb.z = f2bf(xv[c * 4 + 2] * inv_xnorm);
        xb.w = f2bf(xv[c * 4 + 3] * inv_xnorm);
        *reinterpret_cast<ushort4*>(xn + base + j0) = xb;
    }
}

// ---------------- K2: sim row-max via MFMA, 256x256 tile, counted-vmcnt pipeline ----
// 512 threads = 8 waves (2 row-halves x 4 col-quarters), per-wave 128x64 out.
// BK=32, FOUR LDS slots (A[256][32]+B[256][32] = 32 KB each, 128 KB total):
// stage runs 3 K-tiles ahead; at each tile boundary s_waitcnt vmcnt(8) (2 tiles
// = 8 loads stay IN FLIGHT across the barrier, T4) + raw s_barrier (no
// compiler vmcnt(0) drain) + sched_barrier(0). 16 K-tiles (K=512).
// LDS packing: 2 logical 64B rows per 128B LDS row, XOR-swizzle
// byte ^= (((row>>1)&7)<<4) within the super-row (2-way bank alias = free);
// gload_lds dest linear, global SOURCE inverse-swizzled (rule 21).
// Full matrix (512 blocks = exactly 2 rounds of 256 CUs); XCD pin b = bid&7.
__global__ __launch_bounds__(512, 2) void k2_nn(const unsigned short* __restrict__ xn,
                                                float* __restrict__ partial) {
    __shared__ char lds[131072];  // 4 slots x (A 16KB | B 16KB)

    const int tid = threadIdx.x;
    const int wave = tid >> 6;
    const int lane = tid & 63;
    const int r15 = lane & 15;
    const int kgrp = lane >> 4;
    const int wr = wave >> 2;  // 0..1 (row half)
    const int wc = wave & 3;   // 0..3 (col quarter)

    const int bid = blockIdx.x;
    const int b = bid & 7;       // XCD pin
    const int t0 = bid >> 3;     // 0..63
    const int tm = t0 >> 3, tn = t0 & 7;

    const size_t bbase = (size_t)b * TT * DD;
    const unsigned short* Ag = xn + bbase + (size_t)tm * 256 * DD;
    const unsigned short* Bg = xn + bbase + (size_t)tn * 256 * DD;

    f32x4 acc[8][4];
#pragma unroll
    for (int i = 0; i < 8; ++i)
#pragma unroll
        for (int j = 0; j < 4; ++j) acc[i][j] = (f32x4){0.f, 0.f, 0.f, 0.f};

    // ---- stage: 4 gload_lds per thread per K-tile (A:2 + B:2) ----
    // linear dest byte o; super=o>>7; w=(o&127)^((super&7)<<4);
    // row=2*super+(w>>6); col elem=(w&63)>>1  (inverse of the read swizzle)
    auto stage = [&](int slot, int kt) {
#pragma unroll
        for (int c = 0; c < 2; ++c) {
            const int o = c * 8192 + tid * 16;
            const int sup = o >> 7;
            const int w = (o & 127) ^ ((sup & 7) << 4);
            const int row = sup * 2 + (w >> 6);
            const int ce = (w & 63) >> 1;
            const size_t gof = (size_t)row * DD + kt * 32 + ce;
            load_lds16(Ag + gof, lds + slot * 32768 + o);
            load_lds16(Bg + gof, lds + slot * 32768 + 16384 + o);
        }
    };

    // fragment byte offset for logical row R, col-block kgrp (16B)
#define LADDR(R) \
    (((R) >> 1) * 128 + (((((R) & 1) << 6) + (kgrp << 4)) ^ ((((R) >> 1) & 7) << 4)))

    auto compute = [&](int slot) {
        const char* sA = lds + slot * 32768;
        const char* sB = sA + 16384;
        bf16x8 av[8], bv[4];
#pragma unroll
        for (int ni = 0; ni < 4; ++ni) {
            const int R = wc * 64 + ni * 16 + r15;
            bv[ni] = *(const bf16x8*)(sB + LADDR(R));
        }
#pragma unroll
        for (int mi = 0; mi < 8; ++mi) {
            const int R = wr * 128 + mi * 16 + r15;
            av[mi] = *(const bf16x8*)(sA + LADDR(R));
        }
        __builtin_amdgcn_s_setprio(1);
#pragma unroll
        for (int mi = 0; mi < 8; ++mi)
#pragma unroll
            for (int ni = 0; ni < 4; ++ni)
                acc[mi][ni] = __builtin_amdgcn_mfma_f32_16x16x32_bf16(av[mi], bv[ni],
                                                                      acc[mi][ni], 0, 0, 0);
        __builtin_amdgcn_s_setprio(0);
    };

    // prologue: stage tiles 0,1,2 (12 loads); wait tile0 (leave 8 in flight)
    stage(0, 0);
    stage(1, 1);
    stage(2, 2);
    asm volatile("s_waitcnt vmcnt(8)" ::: "memory");
    __builtin_amdgcn_s_barrier();
    __builtin_amdgcn_sched_barrier(0);

#pragma unroll
    for (int t = 0; t < 16; ++t) {
        if (t + 3 < 16) stage((t + 3) & 3, t + 3);  // slot (t-1)&3: reads done last iter
        compute(t & 3);
        if (t < 15) {
            // wait: next tile landed; newest 2 tiles (8 loads) stay in flight
            if (t <= 12)
                asm volatile("s_waitcnt vmcnt(8)" ::: "memory");
            else if (t == 13)
                asm volatile("s_waitcnt vmcnt(4)" ::: "memory");
            else
                asm volatile("s_waitcnt vmcnt(0)" ::: "memory");
            __builtin_amdgcn_s_barrier();
            __builtin_amdgcn_sched_barrier(0);
        }
    }
#undef LADDR

    // ---- epilogue: row-max (fold ni + 16-lane shfl), diagonal masked ----
    // D layout: col = wc*64 + ni*16 + r15, row = wr*128 + mi*16 + kgrp*4 + r
    const bool diag = (tm == tn);
    float rmx[8][4];
#pragma unroll
    for (int mi = 0; mi < 8; ++mi) {
#pragma unroll
        for (int r = 0; r < 4; ++r) {
            const int rl = wr * 128 + mi * 16 + kgrp * 4 + r;
            float v = -2.0f;
#pragma unroll
            for (int ni = 0; ni < 4; ++ni) {
                float e = acc[mi][ni][r];
                if (diag && (wc * 64 + ni * 16 + r15) == rl) e = -2.0f;
                v = fmaxf(v, e);
            }
            v = fmaxf(v, __shfl_xor(v, 1));
            v = fmaxf(v, __shfl_xor(v, 2));
            v = fmaxf(v, __shfl_xor(v, 4));
            v = fmaxf(v, __shfl_xor(v, 8));
            rmx[mi][r] = v;
        }
    }
    __syncthreads();  // all LDS tile reads done; safe to alias rbuf onto lds
    float* rbuf = (float*)lds;  // [256 rows][4 wc]
    if (r15 == 0) {
#pragma unroll
        for (int mi = 0; mi < 8; ++mi)
#pragma unroll
            for (int r = 0; r < 4; ++r)
                rbuf[(wr * 128 + mi * 16 + kgrp * 4 + r) * 4 + wc] = rmx[mi][r];
    }
    __syncthreads();
    if (tid < 256) {
        const float v = fmaxf(fmaxf(rbuf[tid * 4 + 0], rbuf[tid * 4 + 1]),
                              fmaxf(rbuf[tid * 4 + 2], rbuf[tid * 4 + 3]));
        partial[((size_t)b * TT + tm * 256 + tid) * NT2 + tn] = v;
    }
}

// ---------------- K3: reduce partial maxes + gate_nn scale + final write ----------------
// 256 threads = 4 waves; one wave per row; reads bf16 PO, writes f32 out.
__global__ __launch_bounds__(256) void k3_scale(float* __restrict__ out,
                                                const unsigned short* __restrict__ po,
                                                const float* __restrict__ partial,
                                                const float* __restrict__ p_lsn,
                                                const float* __restrict__ p_lwn) {
    const int row = blockIdx.x * 4 + (threadIdx.x >> 6);
    const int lane = threadIdx.x & 63;
    const float sigma_nn = softplus_f(p_lsn[0]);
    const float w_nn = softplus_f(p_lwn[0]);

    float p = partial[(size_t)row * NT2 + (lane & 7)];
    p = fmaxf(p, __shfl_xor(p, 1));
    p = fmaxf(p, __shfl_xor(p, 2));
    p = fmaxf(p, __shfl_xor(p, 4));
    const float g = 1.0f + w_nn * tanh_fast(sigma_nn * 0.5f * (1.0f - p));

    const size_t base = (size_t)row * DD + lane * 8;
    ushort4 p0 = *reinterpret_cast<const ushort4*>(po + base);
    ushort4 p1 = *reinterpret_cast<const ushort4*>(po + base + 4);
    float4 o0, o1;
    o0.x = bf2f(p0.x) * g; o0.y = bf2f(p0.y) * g;
    o0.z = bf2f(p0.z) * g; o0.w = bf2f(p0.w) * g;
    o1.x = bf2f(p1.x) * g; o1.y = bf2f(p1.y) * g;
    o1.z = bf2f(p1.z) * g; o1.w = bf2f(p1.w) * g;
    *reinterpret_cast<float4*>(out + base) = o0;
    *reinterpret_cast<float4*>(out + base + 4) = o1;
}

extern "C" void kernel_launch(void* const* d_in, const int* in_sizes, int n_in,
                              void* d_out, int out_size, void* d_ws, size_t ws_size,
                              hipStream_t stream) {
    const float* x = (const float*)d_in[0];
    const float* ema_mean = (const float*)d_in[1];
    const float* ema_sq = (const float*)d_in[2];
    const float* ema_out = (const float*)d_in[3];
    const float* log_tau = (const float*)d_in[4];
    const float* log_beta_up = (const float*)d_in[5];
    const float* log_beta_dn = (const float*)d_in[6];
    const float* log_gamma = (const float*)d_in[7];
    const float* log_sigma_nn = (const float*)d_in[8];
    const float* log_w_nn = (const float*)d_in[9];

    // ws layout: XN bf16 [B*T*D] (16.78 MB) | PO bf16 [B*T*D] (16.78 MB)
    //            | partial f32[B*T][NT2] (512 KB)
    char* ws = (char*)d_ws;
    unsigned short* XN = (unsigned short*)ws;
    unsigned short* PO = (unsigned short*)(ws + 16777216);
    float* partial = (float*)(ws + 33554432);
    float* out = (float*)d_out;

    hipLaunchKernelGGL(k1_elem, dim3(BB * TT / 4), dim3(256), 0, stream, x, ema_mean, ema_sq,
                       ema_out, log_tau, log_beta_up, log_beta_dn, log_gamma, XN, PO);
    hipLaunchKernelGGL(k2_nn, dim3(BB * 64), dim3(512), 0, stream, XN, partial);
    hipLaunchKernelGGL(k3_scale, dim3(BB * TT / 4), dim3(256), 0, stream, out, PO, partial,
                       log_sigma_nn, log_w_nn);
}